// Round 3
// baseline (95.006 us; speedup 1.0000x reference)
//
#include <hip/hip_runtime.h>
#include <math.h>

// Problem constants (reference: B,S,D = 8,2048,512, all fp32)
#define B 8
#define S 2048
#define D 512

// Algebraic identity: softmax over axis=1 (s) followed by emb.sum(axis=1)
// makes attention a no-op: sum_s attn[b,s,t] == 1, so pooled[b] = sum_t r[b,t,:].
//   out[b] = sigmoid( (sum_t x[b,t,:]) . (Wl @ Wr) + S*(Wl.br) + bl )
// q/v/Wq/bq/Wv/bv are mathematically irrelevant.
//
// Structure (2 kernels, no atomics, no zero-init — all ws words are overwritten):
//   stage1: blocks 0..1023   -> px[b][ch][D] partial column-sums of x
//           blocks 1024..1055-> pw[j][D]     partials of Wl @ Wr
//   stage2: 8 blocks (one per batch) reduce partials -> logit -> sigmoid.
// CH=128 (vs 64 in R2): 1056 blocks ~ 4/CU ~ 16 waves/CU for HBM latency hiding.

#define CH 128           // S-chunks per batch
#define ROWS (S / CH)    // 16 rows per block
#define WBLK 32          // Wl@Wr partial blocks
#define WROWS (D / WBLK) // 16 d-rows per block

__global__ __launch_bounds__(256) void stage1(const float4* __restrict__ x,
                                              const float4* __restrict__ Wr,
                                              const float* __restrict__ Wl,
                                              float4* __restrict__ px,   // [B*CH][D/4]
                                              float4* __restrict__ pw) { // [WBLK][D/4]
    __shared__ float4 sbuf[128];
    const int tid  = threadIdx.x;
    const int col  = tid & 127;   // float4 column 0..127 (covers D=512 floats)
    const int half = tid >> 7;    // 0/1: two rows in flight per iteration
    const int blk  = blockIdx.x;
    float4 acc = {0.f, 0.f, 0.f, 0.f};

    if (blk < B * CH) {
        const int b = blk / CH, ch = blk % CH;
        const float4* p = x + (size_t)(b * S + ch * ROWS + half) * (D / 4) + col;
#pragma unroll
        for (int i = 0; i < ROWS; i += 2) {
            float4 v = p[(size_t)i * (D / 4)];
            acc.x += v.x; acc.y += v.y; acc.z += v.z; acc.w += v.w;
        }
    } else {
        const int j = blk - B * CH;  // 0..31
#pragma unroll
        for (int i = 0; i < WROWS; i += 2) {
            int d = j * WROWS + i + half;
            float wl = Wl[d];
            float4 v = Wr[(size_t)d * (D / 4) + col];
            acc.x += wl * v.x; acc.y += wl * v.y; acc.z += wl * v.z; acc.w += wl * v.w;
        }
    }

    if (half) sbuf[col] = acc;
    __syncthreads();
    if (!half) {
        float4 o = sbuf[col];
        acc.x += o.x; acc.y += o.y; acc.z += o.z; acc.w += o.w;
        if (blk < B * CH) px[(size_t)blk * (D / 4) + col] = acc;
        else              pw[(size_t)(blk - B * CH) * (D / 4) + col] = acc;
    }
}

__global__ __launch_bounds__(512) void stage2(const float* __restrict__ px,
                                              const float* __restrict__ pw,
                                              const float* __restrict__ Wl,
                                              const float* __restrict__ br,
                                              const float* __restrict__ bl,
                                              float* __restrict__ out) {
    const int b = blockIdx.x;
    const int e = threadIdx.x;  // 0..511, one d-element each

    float wsum = 0.f;  // wcomb[e] = sum_d Wl[d]*Wr[d,e]
#pragma unroll
    for (int j = 0; j < WBLK; ++j) wsum += pw[j * D + e];

    float xsum = 0.f;  // xs[b,e] = sum_t x[b,t,e]
#pragma unroll 16
    for (int ch = 0; ch < CH; ++ch) xsum += px[((size_t)b * CH + ch) * D + e];

    float val = xsum * wsum;
    float wb  = Wl[e] * br[e];

    // wave-64 butterfly, then cross-wave via LDS
#pragma unroll
    for (int off = 32; off > 0; off >>= 1) {
        val += __shfl_down(val, off);
        wb  += __shfl_down(wb, off);
    }
    __shared__ float sv[8], sw[8];
    const int w = e >> 6, l = e & 63;
    if (l == 0) { sv[w] = val; sw[w] = wb; }
    __syncthreads();
    if (e == 0) {
        float v = 0.f, wbt = 0.f;
#pragma unroll
        for (int i = 0; i < 8; ++i) { v += sv[i]; wbt += sw[i]; }
        float logit = v + (float)S * wbt + bl[0];
        out[b] = 1.0f / (1.0f + expf(-logit));
    }
}

extern "C" void kernel_launch(void* const* d_in, const int* in_sizes, int n_in,
                              void* d_out, int out_size, void* d_ws, size_t ws_size,
                              hipStream_t stream) {
    // inputs: 0=x 1=Wq 2=bq 3=Wv 4=bv 5=Wr 6=br 7=Wl 8=bl (q/v path unused — identity above)
    const float* x  = (const float*)d_in[0];
    const float* Wr = (const float*)d_in[5];
    const float* br = (const float*)d_in[6];
    const float* Wl = (const float*)d_in[7];
    const float* bl = (const float*)d_in[8];
    float* out = (float*)d_out;

    float* px = (float*)d_ws;            // B*CH*D floats = 2 MB
    float* pw = px + (size_t)B * CH * D; // WBLK*D floats = 64 KB

    stage1<<<B * CH + WBLK, 256, 0, stream>>>((const float4*)x, (const float4*)Wr, Wl,
                                              (float4*)px, (float4*)pw);
    stage2<<<B, 512, 0, stream>>>(px, pw, Wl, br, bl, out);
}

// Round 4
// 92.405 us; speedup vs baseline: 1.0282x; 1.0282x over previous
//
#include <hip/hip_runtime.h>
#include <math.h>

// Problem constants (reference: B,S,D = 8,2048,512, all fp32)
#define B 8
#define S 2048
#define D 512

// Algebraic identity: softmax over axis=1 (s) followed by emb.sum(axis=1)
// makes attention a no-op: sum_s attn[b,s,t] == 1, so pooled[b] = sum_t r[b,t,:].
//   out[b] = sigmoid( (sum_t x[b,t,:]) . (Wl @ Wr) + S*(Wl.br) + bl )
// q/v/Wq/bq/Wv/bv are mathematically irrelevant.
//
// Structure (2 kernels, no atomics, no zero-init — all ws words are overwritten):
//   stage1: blocks 0..511  -> px[b][ch][D] partial column-sums of x
//           blocks 512..543-> pw[j][D]     partials of Wl @ Wr
//   stage2: 8 blocks (one per batch) reduce partials -> logit -> sigmoid.
// CH=64: measured best (R2, 92.7 µs). CH=128 (R3) regressed — stage1 is
// HBM-BW-bound, extra partial traffic outweighed extra latency hiding.

#define CH 64            // S-chunks per batch
#define ROWS (S / CH)    // 32 rows per block
#define WBLK 32          // Wl@Wr partial blocks
#define WROWS (D / WBLK) // 16 d-rows per block

__global__ __launch_bounds__(256) void stage1(const float4* __restrict__ x,
                                              const float4* __restrict__ Wr,
                                              const float* __restrict__ Wl,
                                              float4* __restrict__ px,   // [B*CH][D/4]
                                              float4* __restrict__ pw) { // [WBLK][D/4]
    __shared__ float4 sbuf[128];
    const int tid  = threadIdx.x;
    const int col  = tid & 127;   // float4 column 0..127 (covers D=512 floats)
    const int half = tid >> 7;    // 0/1: two rows in flight per iteration
    const int blk  = blockIdx.x;
    float4 acc = {0.f, 0.f, 0.f, 0.f};

    if (blk < B * CH) {
        const int b = blk / CH, ch = blk % CH;
        const float4* p = x + (size_t)(b * S + ch * ROWS + half) * (D / 4) + col;
#pragma unroll
        for (int i = 0; i < ROWS; i += 2) {
            float4 v = p[(size_t)i * (D / 4)];
            acc.x += v.x; acc.y += v.y; acc.z += v.z; acc.w += v.w;
        }
    } else {
        const int j = blk - B * CH;  // 0..31
#pragma unroll
        for (int i = 0; i < WROWS; i += 2) {
            int d = j * WROWS + i + half;
            float wl = Wl[d];
            float4 v = Wr[(size_t)d * (D / 4) + col];
            acc.x += wl * v.x; acc.y += wl * v.y; acc.z += wl * v.z; acc.w += wl * v.w;
        }
    }

    if (half) sbuf[col] = acc;
    __syncthreads();
    if (!half) {
        float4 o = sbuf[col];
        acc.x += o.x; acc.y += o.y; acc.z += o.z; acc.w += o.w;
        if (blk < B * CH) px[(size_t)blk * (D / 4) + col] = acc;
        else              pw[(size_t)(blk - B * CH) * (D / 4) + col] = acc;
    }
}

__global__ __launch_bounds__(512) void stage2(const float* __restrict__ px,
                                              const float* __restrict__ pw,
                                              const float* __restrict__ Wl,
                                              const float* __restrict__ br,
                                              const float* __restrict__ bl,
                                              float* __restrict__ out) {
    const int b = blockIdx.x;
    const int e = threadIdx.x;  // 0..511, one d-element each

    float wsum = 0.f;  // wcomb[e] = sum_d Wl[d]*Wr[d,e]
#pragma unroll
    for (int j = 0; j < WBLK; ++j) wsum += pw[j * D + e];

    float xsum = 0.f;  // xs[b,e] = sum_t x[b,t,e]
#pragma unroll
    for (int ch = 0; ch < CH; ++ch) xsum += px[((size_t)b * CH + ch) * D + e];

    float val = xsum * wsum;
    float wb  = Wl[e] * br[e];

    // wave-64 butterfly, then cross-wave via LDS
#pragma unroll
    for (int off = 32; off > 0; off >>= 1) {
        val += __shfl_down(val, off);
        wb  += __shfl_down(wb, off);
    }
    __shared__ float sv[8], sw[8];
    const int w = e >> 6, l = e & 63;
    if (l == 0) { sv[w] = val; sw[w] = wb; }
    __syncthreads();
    if (e == 0) {
        float v = 0.f, wbt = 0.f;
#pragma unroll
        for (int i = 0; i < 8; ++i) { v += sv[i]; wbt += sw[i]; }
        float logit = v + (float)S * wbt + bl[0];
        out[b] = 1.0f / (1.0f + expf(-logit));
    }
}

extern "C" void kernel_launch(void* const* d_in, const int* in_sizes, int n_in,
                              void* d_out, int out_size, void* d_ws, size_t ws_size,
                              hipStream_t stream) {
    // inputs: 0=x 1=Wq 2=bq 3=Wv 4=bv 5=Wr 6=br 7=Wl 8=bl (q/v path unused — identity above)
    const float* x  = (const float*)d_in[0];
    const float* Wr = (const float*)d_in[5];
    const float* br = (const float*)d_in[6];
    const float* Wl = (const float*)d_in[7];
    const float* bl = (const float*)d_in[8];
    float* out = (float*)d_out;

    float* px = (float*)d_ws;            // B*CH*D floats = 1 MB
    float* pw = px + (size_t)B * CH * D; // WBLK*D floats = 64 KB

    stage1<<<B * CH + WBLK, 256, 0, stream>>>((const float4*)x, (const float4*)Wr, Wl,
                                              (float4*)px, (float4*)pw);
    stage2<<<B, 512, 0, stream>>>(px, pw, Wl, br, bl, out);
}